// Round 6
// baseline (518.599 us; speedup 1.0000x reference)
//
#include <hip/hip_runtime.h>

#define LR 0.01f

// Problem constants (from reference setup_inputs): B=4, S=2048, D=1024, Ds=256
constexpr int Bc  = 4;
constexpr int Sc  = 2048;
constexpr int Dc  = 1024;
constexpr int Dsc = 256;

// ---------------------------------------------------------------------------
// Tiled fp32 GEMM:  C[M,N] = A[M,K] @ Bm[K,N] + bias[N] (+ resid[M,N] if given)
// Block: 256 threads, 64x64 tile, BK=16, 4x4 micro-tile per thread.
// v7: bm <- blockIdx.x (fast dim) so consecutive dispatch ids share the SMALL
// B-panel (W fits L2 everywhere) and stream each A-panel exactly once,
// instead of 4 XCDs refetching the same A-panel (FETCH was 2x ideal).
// ---------------------------------------------------------------------------
__global__ __launch_bounds__(256) void gemm_bias(
    const float* __restrict__ A, const float* __restrict__ Bm,
    const float* __restrict__ bias, const float* __restrict__ resid,
    float* __restrict__ C, int M, int N, int K) {
  constexpr int BM = 64, BN = 64, BK = 16;
  __shared__ float As[BK][BM + 4];
  __shared__ float Bs[BK][BN + 4];

  const int bm = blockIdx.x * BM;
  const int bn = blockIdx.y * BN;
  const int tx = threadIdx.x & 15;   // 0..15 -> 4 cols each
  const int ty = threadIdx.x >> 4;   // 0..15 -> 4 rows each

  float acc[4][4] = {};

  for (int k0 = 0; k0 < K; k0 += BK) {
    // Load A tile: rows bm..bm+63, cols k0..k0+15  (k fastest -> 64B segments)
    for (int i = threadIdx.x; i < BM * BK; i += 256) {
      int m = i >> 4, k = i & 15;
      As[k][m] = A[(size_t)(bm + m) * K + k0 + k];
    }
    // Load B tile: rows k0..k0+15, cols bn..bn+63 (n fastest -> coalesced)
    for (int i = threadIdx.x; i < BK * BN; i += 256) {
      int k = i >> 6, n = i & 63;
      Bs[k][n] = Bm[(size_t)(k0 + k) * N + bn + n];
    }
    __syncthreads();
#pragma unroll
    for (int k = 0; k < BK; ++k) {
      float a[4], bb[4];
#pragma unroll
      for (int i = 0; i < 4; ++i) a[i] = As[k][ty * 4 + i];
#pragma unroll
      for (int j = 0; j < 4; ++j) bb[j] = Bs[k][tx * 4 + j];
#pragma unroll
      for (int i = 0; i < 4; ++i)
#pragma unroll
        for (int j = 0; j < 4; ++j) acc[i][j] += a[i] * bb[j];
    }
    __syncthreads();
  }

#pragma unroll
  for (int i = 0; i < 4; ++i) {
    int m = bm + ty * 4 + i;
#pragma unroll
    for (int j = 0; j < 4; ++j) {
      int n = bn + tx * 4 + j;
      float v = acc[i][j] + bias[n];
      if (resid) v += resid[(size_t)m * N + n];
      C[(size_t)m * N + n] = v;
    }
  }
}

// ---------------------------------------------------------------------------
// TTT scan v7 — rank-1 deferred update.
// v6 measured 239 cyc/step with ~120 cyc VALU busy: the SERIAL chain
// (dot -> 6-DPP reduce -> readlane -> err -> w-update -> next dot) binds.
// Re-associate: p_{t+1} = f_{t+1}.w_{t+1} = D_t - err_t*C_t with
//   D_t = f_{t+1}.w_t  (depends on w_t, NOT err_t)
//   C_t = f_{t+1}.f_t  (independent of the recurrence)
// Both dots + their DPP reduces pipeline a full step ahead; the tight serial
// chain is only err_t -> p_{t+1} -> err_{t+1} (3 VALU ops). Elapsed becomes
// VALU-issue-bound (~35 instr/step).
// f-rows stream through a 3-deep rotating register bank (X/Y/Z) fed by
// static-offset ds_reads off one incremented pointer (~3 steps = ~220cyc of
// cover > 120cyc ds latency). LDS staging/handoff identical to v6 (proven):
// global_load_lds x16/wave, double-buffered 64-row chunks, counted vmcnt(16).
// ---------------------------------------------------------------------------

template <int CTRL, int RM>
__device__ __forceinline__ float dpp_sum(float v) {
  int moved = __builtin_amdgcn_update_dpp(0, __float_as_int(v), CTRL, RM, 0xF, false);
  return v + __int_as_float(moved);
}

__device__ __forceinline__ void async_copy16(const float* g, float* l) {
  __builtin_amdgcn_global_load_lds(
      (const __attribute__((address_space(1))) unsigned int*)g,
      (__attribute__((address_space(3))) unsigned int*)l, 16, 0, 0);
}

constexpr int RCH = 64;        // rows per LDS chunk (64 x 1KB = 64KB/buffer)
constexpr int NCH = Sc / RCH;  // 32 chunks

__global__ __launch_bounds__(256) void ttt_scan(const float* __restrict__ feat,
                                                float* __restrict__ preds) {
  const int lane = threadIdx.x & 63;
  const int wave = threadIdx.x >> 6;

  // XCD-locality swizzle: XCDs {0,1}->b=0, {2,3}->b=1, {4,5}->b=2, {6,7}->b=3.
  const int bi  = blockIdx.x;                    // 0..255
  const int xcd = bi & 7;
  const int b   = xcd >> 1;                      // 0..3
  const int q   = ((bi >> 3) << 1) | (xcd & 1);  // 0..63 group-of-4 within b
  const int j   = (q << 2) | wave;               // 0..255

  __shared__ float lds[2][RCH * Dsc];  // 128 KB

  const float* fb0 = feat + (size_t)b * Sc * Dsc;
  float* pb0 = preds + (size_t)b * Sc * Dsc + j;

#define STAGE_CHUNK(BUFSEL, T0)                                         \
  {                                                                     \
    _Pragma("unroll")                                                   \
    for (int r_ = 0; r_ < 16; ++r_) {                                   \
      const int row_ = (wave << 4) | r_;                                \
      async_copy16(fb0 + (size_t)((T0) + row_) * Dsc + (lane << 2),     \
                   &lds[BUFSEL][row_ * Dsc]);                           \
    }                                                                   \
  }

// Iteration k: consumes bank (G*, FJN) = row k+1 data; F = f_k (regs);
// err = err_k; w = w_k. Produces p_{k+1} -> vp slot SLOT, w_{k+1}, err_{k+1},
// F <- f_{k+1}.
#define TTT_IT(SLOT, G0, G1, G2, G3, FJN)                                      \
  {                                                                            \
    float dD = fmaf(G1, w1, G0 * w0) + fmaf(G3, w3, G2 * w2);                  \
    float dC = fmaf(G1, F1, G0 * F0) + fmaf(G3, F3, G2 * F2);                  \
    w0 = fmaf(-err, F0, w0); w1 = fmaf(-err, F1, w1);                          \
    w2 = fmaf(-err, F2, w2); w3 = fmaf(-err, F3, w3);                          \
    dD = dpp_sum<0x111, 0xF>(dD); dC = dpp_sum<0x111, 0xF>(dC);                \
    dD = dpp_sum<0x112, 0xF>(dD); dC = dpp_sum<0x112, 0xF>(dC);                \
    dD = dpp_sum<0x114, 0xF>(dD); dC = dpp_sum<0x114, 0xF>(dC);                \
    dD = dpp_sum<0x118, 0xF>(dD); dC = dpp_sum<0x118, 0xF>(dC);                \
    dD = dpp_sum<0x142, 0xA>(dD); dC = dpp_sum<0x142, 0xA>(dC);                \
    dD = dpp_sum<0x143, 0xC>(dD); dC = dpp_sum<0x143, 0xC>(dC);                \
    float D_ = __int_as_float(__builtin_amdgcn_readlane(__float_as_int(dD), 63)); \
    float C_ = __int_as_float(__builtin_amdgcn_readlane(__float_as_int(dC), 63)); \
    float p_ = fmaf(-err, C_, D_);                                             \
    float en_ = LR * (p_ - (FJN));                                             \
    vp = (lane == (SLOT)) ? p_ : vp;                                           \
    err = en_;                                                                 \
    F0 = G0; F1 = G1; F2 = G2; F3 = G3;                                        \
  }

// Load one bank from pA/pAj at float offset OFF (row-relative, imm-foldable).
#define LDBANK(B0, B1, B2, B3, BJ, OFF)  \
  B0 = pA[(OFF) + lane];                 \
  B1 = pA[(OFF) + lane + 64];            \
  B2 = pA[(OFF) + lane + 128];           \
  B3 = pA[(OFF) + lane + 192];           \
  BJ = pAj[(OFF)];

  // Prologue: stage chunks 0 and 1; wait for chunk 0 (16 newest may remain).
  STAGE_CHUNK(0, 0);
  STAGE_CHUNK(1, RCH);
  asm volatile("s_waitcnt vmcnt(16)" ::: "memory");
  __builtin_amdgcn_s_barrier();
  __builtin_amdgcn_sched_barrier(0);

  float w0 = 0.f, w1 = 0.f, w2 = 0.f, w3 = 0.f;
  float F0, F1, F2, F3, err;
  float vp = 0.f;  // slot 0 <=> p_0 = 0 (w_0 = 0)

  // Boot (k=0): F = f_0, err_0 = LR*(p_0 - f_0[j]) = -LR*f_0[j].
  {
    const float* p0 = &lds[0][0];
    F0 = p0[lane]; F1 = p0[lane + 64]; F2 = p0[lane + 128]; F3 = p0[lane + 192];
    err = -LR * p0[j];
  }

#pragma unroll 1
  for (int c = 0; c < NCH; ++c) {
    const int cb = c & 1;
    const float* pA  = &lds[cb][Dsc];      // row 1 (chunk-relative)
    const float* pAj = &lds[cb][Dsc] + j;

    // Banks: X=row s0+1, Y=row s0+2, Z=row s0+3 (3-deep rotation).
    float X0, X1, X2, X3, XJ, Y0, Y1, Y2, Y3, YJ, Z0, Z1, Z2, Z3, ZJ;
    LDBANK(X0, X1, X2, X3, XJ, 0);
    LDBANK(Y0, Y1, Y2, Y3, YJ, 256);
    LDBANK(Z0, Z1, Z2, Z3, ZJ, 512);

    // Main: 20 trips x 3 steps = iterations s = 0..59 (slots 1..60).
#pragma unroll 1
    for (int s0 = 0; s0 < 60; s0 += 3) {
      TTT_IT(s0 + 1, X0, X1, X2, X3, XJ);
      LDBANK(X0, X1, X2, X3, XJ, 768);    // row s0+4
      TTT_IT(s0 + 2, Y0, Y1, Y2, Y3, YJ);
      LDBANK(Y0, Y1, Y2, Y3, YJ, 1024);   // row s0+5
      TTT_IT(s0 + 3, Z0, Z1, Z2, Z3, ZJ);
      LDBANK(Z0, Z1, Z2, Z3, ZJ, 1280);   // row s0+6
      pA += 768; pAj += 768;
    }
    // Tail: s = 60,61,62 (slots 61..63), banks hold rows 61,62,63.
    TTT_IT(61, X0, X1, X2, X3, XJ);
    TTT_IT(62, Y0, Y1, Y2, Y3, YJ);
    TTT_IT(63, Z0, Z1, Z2, Z3, ZJ);

    // Store preds rows c*64..c*64+63 (lane t holds p_{c*64+t}).
    pb0[(size_t)(c * RCH + lane) * Dsc] = vp;

    // Chunk handoff (v6-proven): all waves done reading lds[cb] -> overwrite
    // with chunk c+2 -> counted vmcnt(16) (chunk c+1's loads are older) ->
    // barrier makes c+1 visible.
    __builtin_amdgcn_s_barrier();
    if (c + 2 < NCH) {
      STAGE_CHUNK(cb, (c + 2) * RCH);
      asm volatile("s_waitcnt vmcnt(16)" ::: "memory");
    } else {
      asm volatile("s_waitcnt vmcnt(0)" ::: "memory");
    }
    __builtin_amdgcn_s_barrier();
    __builtin_amdgcn_sched_barrier(0);

    // Boundary iteration k = c*64+63: consumes row c*64+64 = chunk c+1 row 0
    // (buffer cb^1, staged 2 handoffs ago, untouched). p -> slot 0 of new vp.
    if (c + 1 < NCH) {
      const float* pn = &lds[cb ^ 1][0];
      float B0 = pn[lane], B1 = pn[lane + 64], B2 = pn[lane + 128],
            B3 = pn[lane + 192], BJ = pn[j];
      TTT_IT(0, B0, B1, B2, B3, BJ);
    }
  }
#undef LDBANK
#undef TTT_IT
#undef STAGE_CHUNK
}

extern "C" void kernel_launch(void* const* d_in, const int* in_sizes, int n_in,
                              void* d_out, int out_size, void* d_ws, size_t ws_size,
                              hipStream_t stream) {
  const float* x  = (const float*)d_in[0];  // (B,S,D)
  const float* Wd = (const float*)d_in[1];  // (D,Ds)
  const float* bd = (const float*)d_in[2];  // (Ds)
  const float* Wu = (const float*)d_in[3];  // (Ds,D)
  const float* bu = (const float*)d_in[4];  // (D)
  float* out = (float*)d_out;               // (B,S,D)

  float* feat  = (float*)d_ws;                        // B*S*Ds f32 = 8 MB
  float* preds = feat + (size_t)Bc * Sc * Dsc;        // B*S*Ds f32 = 8 MB

  const int M = Bc * Sc;  // 8192
  dim3 blk(256);

  // feat = x @ W_down + b_down   (M=8192, N=256, K=1024)
  gemm_bias<<<dim3(M / 64, Dsc / 64), blk, 0, stream>>>(
      x, Wd, bd, nullptr, feat, M, Dsc, Dc);

  // sequential fast-weight scan -> preds  (1024 independent wave-chains)
  ttt_scan<<<dim3(Bc * Dsc / 4), blk, 0, stream>>>(feat, preds);

  // out = preds @ W_up + b_up + x   (M=8192, N=1024, K=256)
  gemm_bias<<<dim3(M / 64, Dc / 64), blk, 0, stream>>>(
      preds, Wu, bu, x, out, M, Dc, Dsc);
}

// Round 7
// 476.169 us; speedup vs baseline: 1.0891x; 1.0891x over previous
//
#include <hip/hip_runtime.h>

#define LR 0.01f

// Problem constants (from reference setup_inputs): B=4, S=2048, D=1024, Ds=256
constexpr int Bc  = 4;
constexpr int Sc  = 2048;
constexpr int Dc  = 1024;
constexpr int Dsc = 256;

// ---------------------------------------------------------------------------
// Tiled fp32 GEMM:  C[M,N] = A[M,K] @ Bm[K,N] + bias[N] (+ resid[M,N] if given)
// Block: 256 threads, 64x64 tile, BK=16, 4x4 micro-tile per thread.
// ---------------------------------------------------------------------------
__global__ __launch_bounds__(256) void gemm_bias(
    const float* __restrict__ A, const float* __restrict__ Bm,
    const float* __restrict__ bias, const float* __restrict__ resid,
    float* __restrict__ C, int M, int N, int K) {
  constexpr int BM = 64, BN = 64, BK = 16;
  __shared__ float As[BK][BM + 4];
  __shared__ float Bs[BK][BN + 4];

  const int bm = blockIdx.x * BM;
  const int bn = blockIdx.y * BN;
  const int tx = threadIdx.x & 15;   // 0..15 -> 4 cols each
  const int ty = threadIdx.x >> 4;   // 0..15 -> 4 rows each

  float acc[4][4] = {};

  for (int k0 = 0; k0 < K; k0 += BK) {
    for (int i = threadIdx.x; i < BM * BK; i += 256) {
      int m = i >> 4, k = i & 15;
      As[k][m] = A[(size_t)(bm + m) * K + k0 + k];
    }
    for (int i = threadIdx.x; i < BK * BN; i += 256) {
      int k = i >> 6, n = i & 63;
      Bs[k][n] = Bm[(size_t)(k0 + k) * N + bn + n];
    }
    __syncthreads();
#pragma unroll
    for (int k = 0; k < BK; ++k) {
      float a[4], bb[4];
#pragma unroll
      for (int i = 0; i < 4; ++i) a[i] = As[k][ty * 4 + i];
#pragma unroll
      for (int j = 0; j < 4; ++j) bb[j] = Bs[k][tx * 4 + j];
#pragma unroll
      for (int i = 0; i < 4; ++i)
#pragma unroll
        for (int j = 0; j < 4; ++j) acc[i][j] += a[i] * bb[j];
    }
    __syncthreads();
  }

#pragma unroll
  for (int i = 0; i < 4; ++i) {
    int m = bm + ty * 4 + i;
#pragma unroll
    for (int j = 0; j < 4; ++j) {
      int n = bn + tx * 4 + j;
      float v = acc[i][j] + bias[n];
      if (resid) v += resid[(size_t)m * N + n];
      C[(size_t)m * N + n] = v;
    }
  }
}

// ---------------------------------------------------------------------------
// v8: rank-1 deferred scan with PRECOMPUTED adjacent Gram dots.
// v7 regressed (290us, VALUBusy 62%): the deferral removed the reduce from
// the serial chain but DOUBLED issue work (two dots + two DPP chains) -- at
// 1 wave/SIMD, instruction count is the floor. Fix: C_t = f_{t+1}.f_t is
// recurrence-independent -> precompute all B*S dots in adj_dots (parallel,
// ~5us), stage per-chunk into LDS, read as wave-uniform broadcast. Scan step
// = ONE dot + ONE reduce (v6 issue count) with v7's relaxed chain (reduce
// spans 2 steps; tight chain err->p->err = 3 ops).
// ---------------------------------------------------------------------------

template <int CTRL, int RM>
__device__ __forceinline__ float dpp_sum(float v) {
  int moved = __builtin_amdgcn_update_dpp(0, __float_as_int(v), CTRL, RM, 0xF, false);
  return v + __int_as_float(moved);
}

__device__ __forceinline__ void async_copy16(const float* g, float* l) {
  __builtin_amdgcn_global_load_lds(
      (const __attribute__((address_space(1))) unsigned int*)g,
      (__attribute__((address_space(3))) unsigned int*)l, 16, 0, 0);
}

__device__ __forceinline__ void async_copy4(const float* g, float* l) {
  __builtin_amdgcn_global_load_lds(
      (const __attribute__((address_space(1))) unsigned int*)g,
      (__attribute__((address_space(3))) unsigned int*)l, 4, 0, 0);
}

// cadj[b*Sc+t] = f_{t+1} . f_t  (raw dot; t = Sc-1 -> 0, unused)
__global__ __launch_bounds__(256) void adj_dots(const float* __restrict__ feat,
                                                float* __restrict__ cadj) {
  const int lane = threadIdx.x & 63;
  const int gw = blockIdx.x * 4 + (threadIdx.x >> 6);  // 0..B*Sc-1
  const int t = gw & (Sc - 1);
  const float* r = feat + (size_t)gw * Dsc;
  float s = 0.f;
  if (t + 1 < Sc) {
    const float* rn = r + Dsc;
    float a0 = r[lane], a1 = r[lane + 64], a2 = r[lane + 128], a3 = r[lane + 192];
    float b0 = rn[lane], b1 = rn[lane + 64], b2 = rn[lane + 128], b3 = rn[lane + 192];
    s = fmaf(a1, b1, a0 * b0) + fmaf(a3, b3, a2 * b2);
    s = dpp_sum<0x111, 0xF>(s);
    s = dpp_sum<0x112, 0xF>(s);
    s = dpp_sum<0x114, 0xF>(s);
    s = dpp_sum<0x118, 0xF>(s);
    s = dpp_sum<0x142, 0xA>(s);
    s = dpp_sum<0x143, 0xC>(s);
  }
  if (lane == 63) cadj[gw] = s;  // lane 63 holds the full sum
}

constexpr int RCH = 64;        // rows per LDS chunk (64 x 1KB = 64KB/buffer)
constexpr int NCH = Sc / RCH;  // 32 chunks

__global__ __launch_bounds__(256) void ttt_scan(const float* __restrict__ feat,
                                                const float* __restrict__ cadj,
                                                float* __restrict__ preds) {
  const int lane = threadIdx.x & 63;
  const int wave = threadIdx.x >> 6;

  // XCD-locality swizzle: XCDs {0,1}->b=0, {2,3}->b=1, {4,5}->b=2, {6,7}->b=3.
  const int bi  = blockIdx.x;                    // 0..255
  const int xcd = bi & 7;
  const int b   = xcd >> 1;                      // 0..3
  const int q   = ((bi >> 3) << 1) | (xcd & 1);  // 0..63 group-of-4 within b
  const int j   = (q << 2) | wave;               // 0..255

  __shared__ float lds[2][RCH * Dsc];   // 128 KB
  __shared__ float cbuf[2][4][RCH];     // 2 KB (per-wave copy of chunk cadj)

  const float* fb0   = feat + (size_t)b * Sc * Dsc;
  const float* cadjb = cadj + (size_t)b * Sc;
  float* pb0 = preds + (size_t)b * Sc * Dsc + j;

// 17 async loads per wave per stage: 16 feat rows + 1 cadj row-block.
#define STAGE_CHUNK(BUFSEL, T0)                                         \
  {                                                                     \
    _Pragma("unroll")                                                   \
    for (int r_ = 0; r_ < 16; ++r_) {                                   \
      const int row_ = (wave << 4) | r_;                                \
      async_copy16(fb0 + (size_t)((T0) + row_) * Dsc + (lane << 2),     \
                   &lds[BUFSEL][row_ * Dsc]);                           \
    }                                                                   \
    async_copy4(cadjb + (T0) + lane, &cbuf[BUFSEL][wave][0]);           \
  }

// Iteration k: G*/FJN = row k+1 data; CJN = f_{k+1}.f_k; F = f_k; err=err_k;
// w=w_k. Produces p_{k+1} -> vp slot SLOT, w_{k+1}, err_{k+1}, F <- f_{k+1}.
#define TTT_IT(SLOT, G0, G1, G2, G3, FJN, CJN)                                 \
  {                                                                            \
    float dD = fmaf(G1, w1, G0 * w0) + fmaf(G3, w3, G2 * w2); /* f_{k+1}.w_k */\
    w0 = fmaf(-err, F0, w0); w1 = fmaf(-err, F1, w1);                          \
    w2 = fmaf(-err, F2, w2); w3 = fmaf(-err, F3, w3);                          \
    dD = dpp_sum<0x111, 0xF>(dD);                                              \
    dD = dpp_sum<0x112, 0xF>(dD);                                              \
    dD = dpp_sum<0x114, 0xF>(dD);                                              \
    dD = dpp_sum<0x118, 0xF>(dD);                                              \
    dD = dpp_sum<0x142, 0xA>(dD);                                              \
    dD = dpp_sum<0x143, 0xC>(dD);                                              \
    float D_ = __int_as_float(__builtin_amdgcn_readlane(__float_as_int(dD), 63)); \
    float p_ = fmaf(-err, (CJN), D_);                                          \
    float en_ = LR * (p_ - (FJN));                                             \
    vp = (lane == (SLOT)) ? p_ : vp;                                           \
    err = en_;                                                                 \
    F0 = G0; F1 = G1; F2 = G2; F3 = G3;                                        \
  }

// Bank load: 4 per-lane slots + f[j] broadcast + C scalar broadcast.
// OFF is a row-relative float offset (imm-foldable); C index = OFF/256.
#define LDBANK(B0, B1, B2, B3, BJ, BC, OFF)  \
  B0 = pA[(OFF) + lane];                     \
  B1 = pA[(OFF) + lane + 64];                \
  B2 = pA[(OFF) + lane + 128];               \
  B3 = pA[(OFF) + lane + 192];               \
  BJ = pAj[(OFF)];                           \
  BC = pC[(OFF) >> 8];

  // Prologue: stage chunks 0 and 1; wait for chunk 0 (17 newest may remain).
  STAGE_CHUNK(0, 0);
  STAGE_CHUNK(1, RCH);
  asm volatile("s_waitcnt vmcnt(17)" ::: "memory");
  __builtin_amdgcn_s_barrier();
  __builtin_amdgcn_sched_barrier(0);

  float w0 = 0.f, w1 = 0.f, w2 = 0.f, w3 = 0.f;
  float F0, F1, F2, F3, err;
  float vp = 0.f;  // slot 0 <=> p_0 = 0 (w_0 = 0)

  // Boot (k=0): F = f_0, err_0 = LR*(p_0 - f_0[j]) = -LR*f_0[j].
  {
    const float* p0 = &lds[0][0];
    F0 = p0[lane]; F1 = p0[lane + 64]; F2 = p0[lane + 128]; F3 = p0[lane + 192];
    err = -LR * p0[j];
  }

#pragma unroll 1
  for (int c = 0; c < NCH; ++c) {
    const int cb = c & 1;
    const float* pA  = &lds[cb][Dsc];      // row 1 (chunk-relative)
    const float* pAj = &lds[cb][Dsc] + j;
    const float* pC  = &cbuf[cb][wave][0];

    // Banks: X=row s0+1, Y=row s0+2, Z=row s0+3 (3-deep rotation).
    float X0, X1, X2, X3, XJ, XC, Y0, Y1, Y2, Y3, YJ, YC, Z0, Z1, Z2, Z3, ZJ, ZC;
    LDBANK(X0, X1, X2, X3, XJ, XC, 0);
    LDBANK(Y0, Y1, Y2, Y3, YJ, YC, 256);
    LDBANK(Z0, Z1, Z2, Z3, ZJ, ZC, 512);

    // Main: 20 trips x 3 steps = iterations s = 0..59 (slots 1..60).
#pragma unroll 1
    for (int s0 = 0; s0 < 60; s0 += 3) {
      TTT_IT(s0 + 1, X0, X1, X2, X3, XJ, XC);
      LDBANK(X0, X1, X2, X3, XJ, XC, 768);    // row s0+4, C idx s0+3
      TTT_IT(s0 + 2, Y0, Y1, Y2, Y3, YJ, YC);
      LDBANK(Y0, Y1, Y2, Y3, YJ, YC, 1024);   // row s0+5, C idx s0+4
      TTT_IT(s0 + 3, Z0, Z1, Z2, Z3, ZJ, ZC);
      LDBANK(Z0, Z1, Z2, Z3, ZJ, ZC, 1280);   // row s0+6, C idx s0+5
      pA += 768; pAj += 768; pC += 3;
    }
    // Tail: iterations s = 60,61,62 (slots 61..63), banks = rows 61,62,63.
    TTT_IT(61, X0, X1, X2, X3, XJ, XC);
    TTT_IT(62, Y0, Y1, Y2, Y3, YJ, YC);
    TTT_IT(63, Z0, Z1, Z2, Z3, ZJ, ZC);

    // Capture C for the boundary iteration (k = c*64+63) BEFORE cbuf[cb] is
    // overwritten by the handoff staging.
    float cj63 = cbuf[cb][wave][63];

    // Store preds rows c*64..c*64+63 (lane t holds p_{c*64+t}).
    pb0[(size_t)(c * RCH + lane) * Dsc] = vp;

    // Ensure the cj63 ds_read completed before LDS is overwritten.
    asm volatile("s_waitcnt lgkmcnt(0)" ::: "memory");
    __builtin_amdgcn_s_barrier();
    if (c + 2 < NCH) {
      STAGE_CHUNK(cb, (c + 2) * RCH);
      asm volatile("s_waitcnt vmcnt(17)" ::: "memory");
    } else {
      asm volatile("s_waitcnt vmcnt(0)" ::: "memory");
    }
    __builtin_amdgcn_s_barrier();
    __builtin_amdgcn_sched_barrier(0);

    // Boundary iteration k = c*64+63: consumes row (c+1)*64 = chunk c+1 row 0
    // (buffer cb^1, staged 2 handoffs ago, untouched). p -> slot 0 of new vp.
    if (c + 1 < NCH) {
      const float* pn = &lds[cb ^ 1][0];
      float B0 = pn[lane], B1 = pn[lane + 64], B2 = pn[lane + 128],
            B3 = pn[lane + 192], BJ = pn[j];
      TTT_IT(0, B0, B1, B2, B3, BJ, cj63);
    }
  }
#undef LDBANK
#undef TTT_IT
#undef STAGE_CHUNK
}

extern "C" void kernel_launch(void* const* d_in, const int* in_sizes, int n_in,
                              void* d_out, int out_size, void* d_ws, size_t ws_size,
                              hipStream_t stream) {
  const float* x  = (const float*)d_in[0];  // (B,S,D)
  const float* Wd = (const float*)d_in[1];  // (D,Ds)
  const float* bd = (const float*)d_in[2];  // (Ds)
  const float* Wu = (const float*)d_in[3];  // (Ds,D)
  const float* bu = (const float*)d_in[4];  // (D)
  float* out = (float*)d_out;               // (B,S,D)

  float* feat  = (float*)d_ws;                        // B*S*Ds f32 = 8 MB
  float* preds = feat + (size_t)Bc * Sc * Dsc;        // B*S*Ds f32 = 8 MB
  float* cadj  = preds + (size_t)Bc * Sc * Dsc;       // B*S f32 = 32 KB

  const int M = Bc * Sc;  // 8192
  dim3 blk(256);

  // feat = x @ W_down + b_down   (M=8192, N=256, K=1024)
  gemm_bias<<<dim3(M / 64, Dsc / 64), blk, 0, stream>>>(
      x, Wd, bd, nullptr, feat, M, Dsc, Dc);

  // adjacent-row Gram dots (recurrence-independent, fully parallel)
  adj_dots<<<dim3(Bc * Sc / 4), blk, 0, stream>>>(feat, cadj);

  // sequential fast-weight scan -> preds  (1024 independent wave-chains)
  ttt_scan<<<dim3(Bc * Dsc / 4), blk, 0, stream>>>(feat, cadj, preds);

  // out = preds @ W_up + b_up + x   (M=8192, N=1024, K=256)
  gemm_bias<<<dim3(M / 64, Dc / 64), blk, 0, stream>>>(
      preds, Wu, bu, x, out, M, Dc, Dsc);
}

// Round 8
// 456.467 us; speedup vs baseline: 1.1361x; 1.0432x over previous
//
#include <hip/hip_runtime.h>

#define LR 0.01f

// Problem constants (from reference setup_inputs): B=4, S=2048, D=1024, Ds=256
constexpr int Bc  = 4;
constexpr int Sc  = 2048;
constexpr int Dc  = 1024;
constexpr int Dsc = 256;

// ---------------------------------------------------------------------------
// Tiled fp32 GEMM:  C[M,N] = A[M,K] @ Bm[K,N] + bias[N] (+ resid[M,N] if given)
// ---------------------------------------------------------------------------
__global__ __launch_bounds__(256) void gemm_bias(
    const float* __restrict__ A, const float* __restrict__ Bm,
    const float* __restrict__ bias, const float* __restrict__ resid,
    float* __restrict__ C, int M, int N, int K) {
  constexpr int BM = 64, BN = 64, BK = 16;
  __shared__ float As[BK][BM + 4];
  __shared__ float Bs[BK][BN + 4];

  const int bm = blockIdx.x * BM;
  const int bn = blockIdx.y * BN;
  const int tx = threadIdx.x & 15;
  const int ty = threadIdx.x >> 4;

  float acc[4][4] = {};

  for (int k0 = 0; k0 < K; k0 += BK) {
    for (int i = threadIdx.x; i < BM * BK; i += 256) {
      int m = i >> 4, k = i & 15;
      As[k][m] = A[(size_t)(bm + m) * K + k0 + k];
    }
    for (int i = threadIdx.x; i < BK * BN; i += 256) {
      int k = i >> 6, n = i & 63;
      Bs[k][n] = Bm[(size_t)(k0 + k) * N + bn + n];
    }
    __syncthreads();
#pragma unroll
    for (int k = 0; k < BK; ++k) {
      float a[4], bb[4];
#pragma unroll
      for (int i = 0; i < 4; ++i) a[i] = As[k][ty * 4 + i];
#pragma unroll
      for (int j = 0; j < 4; ++j) bb[j] = Bs[k][tx * 4 + j];
#pragma unroll
      for (int i = 0; i < 4; ++i)
#pragma unroll
        for (int j = 0; j < 4; ++j) acc[i][j] += a[i] * bb[j];
    }
    __syncthreads();
  }

#pragma unroll
  for (int i = 0; i < 4; ++i) {
    int m = bm + ty * 4 + i;
#pragma unroll
    for (int j = 0; j < 4; ++j) {
      int n = bn + tx * 4 + j;
      float v = acc[i][j] + bias[n];
      if (resid) v += resid[(size_t)m * N + n];
      C[(size_t)m * N + n] = v;
    }
  }
}

// ---------------------------------------------------------------------------
// v9: chunked (depth-32) fast-weight scan.
// v8 post-mortem: VALUBusy 50% = fully-serial VALU chain; the dot+DPP reduce
// was still inside every iteration (deferral depth 1 insufficient).
// Chunked identity: within a chunk, pred_t = f_t.W_c - sum_{s<t} A[t][s] e_s,
// with W_c FROZEN at chunk start and A = Gram(F) precomputed in parallel.
// -> the 32 per-chunk P0 dots are independent (pipeline with full ILP);
// -> the serial recurrence is readlane -> 1 FMA -> readlane (~14 cyc);
// -> W updated once per chunk (acc via broadcast scalar, no reduce).
// gram_chunks precomputes Ahat[b][c][t][s] = LR*(f_s.f_t), strict lower,
// [t][s] layout so the scan's A-read (lane=s, imm offset t) is conflict-free.
// ---------------------------------------------------------------------------

template <int CTRL, int RM>
__device__ __forceinline__ float dpp_sum(float v) {
  int moved = __builtin_amdgcn_update_dpp(0, __float_as_int(v), CTRL, RM, 0xF, false);
  return v + __int_as_float(moved);
}

__device__ __forceinline__ void async_copy16(const float* g, float* l) {
  __builtin_amdgcn_global_load_lds(
      (const __attribute__((address_space(1))) unsigned int*)g,
      (__attribute__((address_space(3))) unsigned int*)l, 16, 0, 0);
}

constexpr int RCH = 32;        // rows per chunk
constexpr int NCH = Sc / RCH;  // 64 chunks

// Ahat[b*NCH+c][t][s] = (s>t) ? LR * dot(f_{c*32+s}, f_{c*32+t}) : 0
__global__ __launch_bounds__(256) void gram_chunks(const float* __restrict__ feat,
                                                   float* __restrict__ Ahat) {
  const int bc = blockIdx.x;  // 0..B*NCH-1
  __shared__ float Fl[32 * 260];  // +4 pad breaks the row-stride bank conflict
  const float* src = feat + (size_t)bc * RCH * Dsc;
  for (int i = threadIdx.x; i < 32 * 256; i += 256) {
    int r = i >> 8, cc = i & 255;
    Fl[r * 260 + cc] = src[i];
  }
  __syncthreads();
  float* Ab = Ahat + (size_t)bc * 1024;
#pragma unroll
  for (int k2 = 0; k2 < 4; ++k2) {
    int idx = threadIdx.x + (k2 << 8);
    int t = idx >> 5, s = idx & 31;
    float sum = 0.f;
    if (s > t) {
      const float4* fs = (const float4*)&Fl[s * 260];
      const float4* ft = (const float4*)&Fl[t * 260];
#pragma unroll
      for (int i = 0; i < 64; ++i) {
        float4 a = fs[i], b = ft[i];
        sum = fmaf(a.x, b.x, sum); sum = fmaf(a.y, b.y, sum);
        sum = fmaf(a.z, b.z, sum); sum = fmaf(a.w, b.w, sum);
      }
      sum *= LR;
    }
    Ab[idx] = sum;
  }
}

__global__ __launch_bounds__(256) void ttt_scan(const float* __restrict__ feat,
                                                const float* __restrict__ Ahat,
                                                float* __restrict__ preds) {
  const int lane = threadIdx.x & 63;
  const int wave = threadIdx.x >> 6;

  // XCD-locality swizzle (verified: FETCH 32.8 -> 8.2 MB).
  const int bi  = blockIdx.x;                    // 0..255
  const int xcd = bi & 7;
  const int b   = xcd >> 1;                      // 0..3
  const int q   = ((bi >> 3) << 1) | (xcd & 1);  // 0..63
  const int j   = (q << 2) | wave;               // 0..255

  __shared__ float ldsF[2][RCH * Dsc];  // 64 KB
  __shared__ float ldsA[2][RCH * RCH];  // 8 KB

  const float* fb0 = feat + (size_t)b * Sc * Dsc;
  const float* Ag  = Ahat + (size_t)b * NCH * 1024;
  float* pb0 = preds + (size_t)b * Sc * Dsc + j;

// 9 async ops per wave per stage: 8 feat rows (16B/lane) + 1/4 of Ahat chunk.
#define STAGE(BUF, C0)                                                    \
  {                                                                       \
    _Pragma("unroll")                                                     \
    for (int r_ = 0; r_ < 8; ++r_) {                                      \
      const int row_ = (wave << 3) | r_;                                  \
      async_copy16(fb0 + (size_t)((C0) * RCH + row_) * Dsc + (lane << 2), \
                   &ldsF[BUF][row_ * Dsc]);                               \
    }                                                                     \
    async_copy16(Ag + (size_t)(C0) * 1024 + (wave << 8) + (lane << 2),    \
                 &ldsA[BUF][wave << 8]);                                  \
  }

// Load F row R into bank K (4 per-lane slots + f[R][j] broadcast).
#define LOADROW(R, K)                         \
  B##K##0 = pF[(R) * 256 + lane];             \
  B##K##1 = pF[(R) * 256 + lane + 64];        \
  B##K##2 = pF[(R) * 256 + lane + 128];       \
  B##K##3 = pF[(R) * 256 + lane + 192];       \
  FJ##K   = pF[(R) * 256 + j];

// A column for solve step T2: VA[K] = Ahat[T2][lane] (lanes 0..31; 32..63 dup).
#define LOADA(T2, K) VA##K = pAl[(T2) * 32];

// P0 compute for row R (independent of the recurrence: uses frozen w).
#define P0C(R, K)                                                              \
  {                                                                            \
    float d_ = fmaf(B##K##1, w1, B##K##0 * w0) + fmaf(B##K##3, w3, B##K##2 * w2); \
    d_ = dpp_sum<0x111, 0xF>(d_);                                              \
    d_ = dpp_sum<0x112, 0xF>(d_);                                              \
    d_ = dpp_sum<0x114, 0xF>(d_);                                              \
    d_ = dpp_sum<0x118, 0xF>(d_);                                              \
    d_ = dpp_sum<0x142, 0xA>(d_);                                              \
    d_ = dpp_sum<0x143, 0xC>(d_);                                              \
    float p0_ = __int_as_float(__builtin_amdgcn_readlane(__float_as_int(d_), 63)); \
    float bb_ = LR * (p0_ - FJ##K);                                            \
    v_base = (lane == (R)) ? bb_ : v_base;                                     \
    v_fja  = (lane == (R)) ? FJ##K : v_fja;                                    \
  }

// Serial solve step T: e_T = (base+upd)[T]; upd -= e_T*A; acc += e_T*f_T.
#define SOLVE(T, KS)                                                           \
  {                                                                            \
    float vt_ = v_base + v_upd;                                                \
    float se_ = __int_as_float(__builtin_amdgcn_readlane(__float_as_int(vt_), (T))); \
    v_upd = fmaf(-se_, VA##KS, v_upd);                                         \
    acc0 = fmaf(se_, B##KS##0, acc0);                                          \
    acc1 = fmaf(se_, B##KS##1, acc1);                                          \
    acc2 = fmaf(se_, B##KS##2, acc2);                                          \
    acc3 = fmaf(se_, B##KS##3, acc3);                                          \
  }

#define ST_FULL(T, KS, KC) \
  SOLVE(T, KS) LOADROW((T) + 4, KS) LOADA((T) + 2, KC) P0C((T) + 2, KC)
#define ST_NOLOAD(T, KS, KC) \
  SOLVE(T, KS) LOADA((T) + 2, KC) P0C((T) + 2, KC)
#define ST_TAIL(T, KS) SOLVE(T, KS)

  // Prologue: stage chunks 0,1; wait for chunk 0 (chunk 1's 9 may remain).
  STAGE(0, 0);
  STAGE(1, 1);
  asm volatile("s_waitcnt vmcnt(9)" ::: "memory");
  __builtin_amdgcn_s_barrier();
  __builtin_amdgcn_sched_barrier(0);

  float w0 = 0.f, w1 = 0.f, w2 = 0.f, w3 = 0.f;

#pragma unroll 1
  for (int c = 0; c < NCH; ++c) {
    const int cb = c & 1;
    const float* pF  = &ldsF[cb][0];
    const float* pAl = &ldsA[cb][lane & 31];

    float acc0 = 0.f, acc1 = 0.f, acc2 = 0.f, acc3 = 0.f;
    float v_base = 0.f, v_upd = 0.f, v_fja = 0.f;
    float B00, B01, B02, B03, FJ0, B10, B11, B12, B13, FJ1;
    float B20, B21, B22, B23, FJ2, B30, B31, B32, B33, FJ3;
    float VA0, VA1, VA2, VA3;

    // Chunk prologue: rows 0..3, A cols 0,1, P0 rows 0,1.
    LOADROW(0, 0) LOADROW(1, 1) LOADROW(2, 2) LOADROW(3, 3)
    LOADA(0, 0) LOADA(1, 1)
    P0C(0, 0) P0C(1, 1)

    ST_FULL(0, 0, 2)  ST_FULL(1, 1, 3)  ST_FULL(2, 2, 0)  ST_FULL(3, 3, 1)
    ST_FULL(4, 0, 2)  ST_FULL(5, 1, 3)  ST_FULL(6, 2, 0)  ST_FULL(7, 3, 1)
    ST_FULL(8, 0, 2)  ST_FULL(9, 1, 3)  ST_FULL(10, 2, 0) ST_FULL(11, 3, 1)
    ST_FULL(12, 0, 2) ST_FULL(13, 1, 3) ST_FULL(14, 2, 0) ST_FULL(15, 3, 1)
    ST_FULL(16, 0, 2) ST_FULL(17, 1, 3) ST_FULL(18, 2, 0) ST_FULL(19, 3, 1)
    ST_FULL(20, 0, 2) ST_FULL(21, 1, 3) ST_FULL(22, 2, 0) ST_FULL(23, 3, 1)
    ST_FULL(24, 0, 2) ST_FULL(25, 1, 3) ST_FULL(26, 2, 0) ST_FULL(27, 3, 1)
    ST_NOLOAD(28, 0, 2) ST_NOLOAD(29, 1, 3)
    ST_TAIL(30, 2) ST_TAIL(31, 3)

    // preds: pred_t = e_t/LR + f_t[j]  (lane t, t<32).
    float v_out = fmaf(v_base + v_upd, 100.0f, v_fja);
    if (lane < 32) pb0[(size_t)(c * RCH + lane) * Dsc] = v_out;

    // Deferred W update (once per chunk).
    w0 -= acc0; w1 -= acc1; w2 -= acc2; w3 -= acc3;

    // Handoff (v6-proven): barrier -> stage c+2 over buf cb -> counted
    // vmcnt(9) (chunk c+1's 9 loads are older) -> barrier.
    __builtin_amdgcn_s_barrier();
    if (c + 2 < NCH) {
      STAGE(cb, c + 2);
      asm volatile("s_waitcnt vmcnt(9)" ::: "memory");
    } else {
      asm volatile("s_waitcnt vmcnt(0)" ::: "memory");
    }
    __builtin_amdgcn_s_barrier();
    __builtin_amdgcn_sched_barrier(0);
  }
#undef ST_FULL
#undef ST_NOLOAD
#undef ST_TAIL
#undef SOLVE
#undef P0C
#undef LOADA
#undef LOADROW
#undef STAGE
}

extern "C" void kernel_launch(void* const* d_in, const int* in_sizes, int n_in,
                              void* d_out, int out_size, void* d_ws, size_t ws_size,
                              hipStream_t stream) {
  const float* x  = (const float*)d_in[0];  // (B,S,D)
  const float* Wd = (const float*)d_in[1];  // (D,Ds)
  const float* bd = (const float*)d_in[2];  // (Ds)
  const float* Wu = (const float*)d_in[3];  // (Ds,D)
  const float* bu = (const float*)d_in[4];  // (D)
  float* out = (float*)d_out;               // (B,S,D)

  float* feat  = (float*)d_ws;                        // B*S*Ds f32 = 8 MB
  float* preds = feat + (size_t)Bc * Sc * Dsc;        // 8 MB
  float* Ahat  = preds + (size_t)Bc * Sc * Dsc;       // B*NCH*1024 f32 = 1 MB

  const int M = Bc * Sc;  // 8192
  dim3 blk(256);

  // feat = x @ W_down + b_down   (M=8192, N=256, K=1024)
  gemm_bias<<<dim3(M / 64, Dsc / 64), blk, 0, stream>>>(
      x, Wd, bd, nullptr, feat, M, Dsc, Dc);

  // per-chunk strict-lower Gram matrices (parallel, recurrence-independent)
  gram_chunks<<<dim3(Bc * NCH), blk, 0, stream>>>(feat, Ahat);

  // chunked sequential scan -> preds
  ttt_scan<<<dim3(Bc * Dsc / 4), blk, 0, stream>>>(feat, Ahat, preds);

  // out = preds @ W_up + b_up + x   (M=8192, N=1024, K=256)
  gemm_bias<<<dim3(M / 64, Dc / 64), blk, 0, stream>>>(
      preds, Wu, bu, x, out, M, Dc, Dsc);
}

// Round 10
// 339.441 us; speedup vs baseline: 1.5278x; 1.3448x over previous
//
#include <hip/hip_runtime.h>

#define LR 0.01f

// Problem constants (from reference setup_inputs): B=4, S=2048, D=1024, Ds=256
constexpr int Bc  = 4;
constexpr int Sc  = 2048;
constexpr int Dc  = 1024;
constexpr int Dsc = 256;

// ---------------------------------------------------------------------------
// Tiled fp32 GEMM:  C[M,N] = A[M,K] @ Bm[K,N] + bias[N] (+ resid[M,N] if given)
// v10 layout: A-tile stored transposed As[m][k] (stride-1 stores kill the
// 8-way write conflict, SQ_LDS_BANK_CONFLICT was 1.05M), float4 LDS reads
// (2 b128 per 16 FMAs), float4 epilogue.
// ---------------------------------------------------------------------------
__global__ __launch_bounds__(256) void gemm_bias(
    const float* __restrict__ A, const float* __restrict__ Bm,
    const float* __restrict__ bias, const float* __restrict__ resid,
    float* __restrict__ C, int M, int N, int K) {
  constexpr int BM = 64, BN = 64, BK = 16;
  __shared__ float As[BM][BK + 4];  // [64][20]: row 80B, f4-aligned
  __shared__ float Bs[BK][BN + 4];  // [16][68]: row 272B, f4-aligned

  const int bm = blockIdx.x * BM;
  const int bn = blockIdx.y * BN;
  const int tx = threadIdx.x & 15;   // 0..15 -> 4 cols each
  const int ty = threadIdx.x >> 4;   // 0..15 -> 4 rows each

  float acc[4][4] = {};

  for (int k0 = 0; k0 < K; k0 += BK) {
#pragma unroll
    for (int qq = 0; qq < 4; ++qq) {
      int m = ty + 16 * qq;
      As[m][tx] = A[(size_t)(bm + m) * K + k0 + tx];
    }
#pragma unroll
    for (int qq = 0; qq < 4; ++qq) {
      int i = threadIdx.x + 256 * qq;
      int k = i >> 6, n = i & 63;
      Bs[k][n] = Bm[(size_t)(k0 + k) * N + bn + n];
    }
    __syncthreads();
#pragma unroll
    for (int k4 = 0; k4 < BK; k4 += 4) {
      float4 a0 = *(const float4*)&As[ty * 4 + 0][k4];
      float4 a1 = *(const float4*)&As[ty * 4 + 1][k4];
      float4 a2 = *(const float4*)&As[ty * 4 + 2][k4];
      float4 a3 = *(const float4*)&As[ty * 4 + 3][k4];
      float4 b0 = *(const float4*)&Bs[k4 + 0][tx * 4];
      float4 b1 = *(const float4*)&Bs[k4 + 1][tx * 4];
      float4 b2 = *(const float4*)&Bs[k4 + 2][tx * 4];
      float4 b3 = *(const float4*)&Bs[k4 + 3][tx * 4];
#define ROWI(AI)                                          \
      acc[AI][0] = fmaf(a##AI.x, b0.x, acc[AI][0]);       \
      acc[AI][1] = fmaf(a##AI.x, b0.y, acc[AI][1]);       \
      acc[AI][2] = fmaf(a##AI.x, b0.z, acc[AI][2]);       \
      acc[AI][3] = fmaf(a##AI.x, b0.w, acc[AI][3]);       \
      acc[AI][0] = fmaf(a##AI.y, b1.x, acc[AI][0]);       \
      acc[AI][1] = fmaf(a##AI.y, b1.y, acc[AI][1]);       \
      acc[AI][2] = fmaf(a##AI.y, b1.z, acc[AI][2]);       \
      acc[AI][3] = fmaf(a##AI.y, b1.w, acc[AI][3]);       \
      acc[AI][0] = fmaf(a##AI.z, b2.x, acc[AI][0]);       \
      acc[AI][1] = fmaf(a##AI.z, b2.y, acc[AI][1]);       \
      acc[AI][2] = fmaf(a##AI.z, b2.z, acc[AI][2]);       \
      acc[AI][3] = fmaf(a##AI.z, b2.w, acc[AI][3]);       \
      acc[AI][0] = fmaf(a##AI.w, b3.x, acc[AI][0]);       \
      acc[AI][1] = fmaf(a##AI.w, b3.y, acc[AI][1]);       \
      acc[AI][2] = fmaf(a##AI.w, b3.z, acc[AI][2]);       \
      acc[AI][3] = fmaf(a##AI.w, b3.w, acc[AI][3]);
      ROWI(0) ROWI(1) ROWI(2) ROWI(3)
#undef ROWI
    }
    __syncthreads();
  }

  float4 bias4 = *(const float4*)&bias[bn + tx * 4];
#pragma unroll
  for (int i = 0; i < 4; ++i) {
    int m = bm + ty * 4 + i;
    float4 v;
    v.x = acc[i][0] + bias4.x;
    v.y = acc[i][1] + bias4.y;
    v.z = acc[i][2] + bias4.z;
    v.w = acc[i][3] + bias4.w;
    if (resid) {
      float4 r = *(const float4*)&resid[(size_t)m * N + bn + tx * 4];
      v.x += r.x; v.y += r.y; v.z += r.z; v.w += r.w;
    }
    *(float4*)&C[(size_t)m * N + bn + tx * 4] = v;
  }
}

// ---------------------------------------------------------------------------
// v11 scan: chunked (depth-32), bb routed through ROTATING UNIFORM SCALARS.
// v10 failed (absmax 1.7e9 ~ 1%/step exponential growth = stale bb in the
// recurrence): the float2 ds_write / float ds_read round-trip of bb through
// LDS is the suspect mechanism. v11 removes LDS from the bb path entirely:
// P0C(R) ends with readlane(d_,63) -> uniform bb in per-bank scalar SB##K,
// written 2 steps before SOLVE(R) consumes it (DPP chain stays off the
// serial path -- fixing v9's serializer). SOLVE(T): se = SB + readlane(
// v_upd, T); chain = readlane+add+fma ~16cyc. e_T captured off-chain via
// cndmask (vp); f_j via v9's proven cndmask (v_fja).
// Staging/handoff/gram identical to v9 (correctness-proven).
// ---------------------------------------------------------------------------

template <int CTRL, int RM>
__device__ __forceinline__ float dpp_sum(float v) {
  int moved = __builtin_amdgcn_update_dpp(0, __float_as_int(v), CTRL, RM, 0xF, false);
  return v + __int_as_float(moved);
}

__device__ __forceinline__ void async_copy16(const float* g, float* l) {
  __builtin_amdgcn_global_load_lds(
      (const __attribute__((address_space(1))) unsigned int*)g,
      (__attribute__((address_space(3))) unsigned int*)l, 16, 0, 0);
}

constexpr int RCH = 32;        // rows per chunk
constexpr int NCH = Sc / RCH;  // 64 chunks

// Ahat[b*NCH+c][t][s] = (s>t) ? LR * dot(f_{c*32+s}, f_{c*32+t}) : 0
__global__ __launch_bounds__(256) void gram_chunks(const float* __restrict__ feat,
                                                   float* __restrict__ Ahat) {
  const int bc = blockIdx.x;  // 0..B*NCH-1
  __shared__ float Fl[32 * 260];
  const float* src = feat + (size_t)bc * RCH * Dsc;
  for (int i = threadIdx.x; i < 32 * 256; i += 256) {
    int r = i >> 8, cc = i & 255;
    Fl[r * 260 + cc] = src[i];
  }
  __syncthreads();
  float* Ab = Ahat + (size_t)bc * 1024;
#pragma unroll
  for (int k2 = 0; k2 < 4; ++k2) {
    int idx = threadIdx.x + (k2 << 8);
    int t = idx >> 5, s = idx & 31;
    float sum = 0.f;
    if (s > t) {
      const float4* fs = (const float4*)&Fl[s * 260];
      const float4* ft = (const float4*)&Fl[t * 260];
#pragma unroll
      for (int i = 0; i < 64; ++i) {
        float4 a = fs[i], b = ft[i];
        sum = fmaf(a.x, b.x, sum); sum = fmaf(a.y, b.y, sum);
        sum = fmaf(a.z, b.z, sum); sum = fmaf(a.w, b.w, sum);
      }
      sum *= LR;
    }
    Ab[idx] = sum;
  }
}

__global__ __launch_bounds__(256) void ttt_scan(const float* __restrict__ feat,
                                                const float* __restrict__ Ahat,
                                                float* __restrict__ preds) {
  const int lane = threadIdx.x & 63;
  const int wave = threadIdx.x >> 6;

  // XCD-locality swizzle (verified: FETCH 32.8 -> 8.2 MB).
  const int bi  = blockIdx.x;                    // 0..255
  const int xcd = bi & 7;
  const int b   = xcd >> 1;                      // 0..3
  const int q   = ((bi >> 3) << 1) | (xcd & 1);  // 0..63
  const int j   = (q << 2) | wave;               // 0..255

  __shared__ float ldsF[2][RCH * Dsc];  // 64 KB
  __shared__ float ldsA[2][RCH * RCH];  // 8 KB

  const float* fb0 = feat + (size_t)b * Sc * Dsc;
  const float* Ag  = Ahat + (size_t)b * NCH * 1024;
  float* pb0 = preds + (size_t)b * Sc * Dsc + j;

// 9 async ops per wave per stage: 8 feat rows (16B/lane) + 1/4 of Ahat chunk.
#define STAGE(BUF, C0)                                                    \
  {                                                                       \
    _Pragma("unroll")                                                     \
    for (int r_ = 0; r_ < 8; ++r_) {                                      \
      const int row_ = (wave << 3) | r_;                                  \
      async_copy16(fb0 + (size_t)((C0) * RCH + row_) * Dsc + (lane << 2), \
                   &ldsF[BUF][row_ * Dsc]);                               \
    }                                                                     \
    async_copy16(Ag + (size_t)(C0) * 1024 + (wave << 8) + (lane << 2),    \
                 &ldsA[BUF][wave << 8]);                                  \
  }

// Load F row R into bank K (4 per-lane slots + f[R][j] broadcast).
#define LOADROW(R, K)                         \
  B##K##0 = pF[(R) * 256 + lane];             \
  B##K##1 = pF[(R) * 256 + lane + 64];        \
  B##K##2 = pF[(R) * 256 + lane + 128];       \
  B##K##3 = pF[(R) * 256 + lane + 192];       \
  FJ##K   = pF[(R) * 256 + j];

// A row for solve step T2 across lanes: VA[lane] = Ahat[T2][lane&31].
#define LOADA(T2, K) VA##K = pAl[(T2) * 32];

// P0 for row R: dot(f_R, frozen w) -> DPP reduce -> uniform bb into SB##K.
// Off the serial chain (consumed by SOLVE(R) two steps later). f_R[j]
// captured per-lane (lane R) for the epilogue via off-chain cndmask.
#define P0C(R, K)                                                              \
  {                                                                            \
    float d_ = fmaf(B##K##1, w1, B##K##0 * w0) + fmaf(B##K##3, w3, B##K##2 * w2); \
    d_ = dpp_sum<0x111, 0xF>(d_);                                              \
    d_ = dpp_sum<0x112, 0xF>(d_);                                              \
    d_ = dpp_sum<0x114, 0xF>(d_);                                              \
    d_ = dpp_sum<0x118, 0xF>(d_);                                              \
    d_ = dpp_sum<0x142, 0xA>(d_);                                              \
    d_ = dpp_sum<0x143, 0xC>(d_);                                              \
    float p0_ = __int_as_float(__builtin_amdgcn_readlane(__float_as_int(d_), 63)); \
    SB##K = LR * (p0_ - FJ##K);                                                \
    v_fja = (lane == (R)) ? FJ##K : v_fja;                                     \
  }

// Serial solve step T: e_T = SB + v_upd[T]; upd -= e_T*A_row; acc += e_T*f_T.
// vp capture (lane T) is off-chain.
#define SOLVE(T, KS)                                                           \
  {                                                                            \
    float rl_ = __int_as_float(__builtin_amdgcn_readlane(__float_as_int(v_upd), (T))); \
    float se_ = SB##KS + rl_;                                                  \
    v_upd = fmaf(-se_, VA##KS, v_upd);                                         \
    acc0 = fmaf(se_, B##KS##0, acc0);                                          \
    acc1 = fmaf(se_, B##KS##1, acc1);                                          \
    acc2 = fmaf(se_, B##KS##2, acc2);                                          \
    acc3 = fmaf(se_, B##KS##3, acc3);                                          \
    vp = (lane == (T)) ? se_ : vp;                                             \
  }

#define ST_FULL(T, KS, KC) \
  SOLVE(T, KS) LOADROW((T) + 4, KS) LOADA((T) + 2, KC) P0C((T) + 2, KC)
#define ST_NOLOAD(T, KS, KC) \
  SOLVE(T, KS) LOADA((T) + 2, KC) P0C((T) + 2, KC)
#define ST_TAIL(T, KS) SOLVE(T, KS)

  // Prologue: stage chunks 0,1; wait for chunk 0 (chunk 1's 9 may remain).
  STAGE(0, 0);
  STAGE(1, 1);
  asm volatile("s_waitcnt vmcnt(9)" ::: "memory");
  __builtin_amdgcn_s_barrier();
  __builtin_amdgcn_sched_barrier(0);

  float w0 = 0.f, w1 = 0.f, w2 = 0.f, w3 = 0.f;

#pragma unroll 1
  for (int c = 0; c < NCH; ++c) {
    const int cb = c & 1;
    const float* pF  = &ldsF[cb][0];
    const float* pAl = &ldsA[cb][lane & 31];

    float acc0 = 0.f, acc1 = 0.f, acc2 = 0.f, acc3 = 0.f;
    float v_upd = 0.f, vp = 0.f, v_fja = 0.f;
    float B00, B01, B02, B03, FJ0, B10, B11, B12, B13, FJ1;
    float B20, B21, B22, B23, FJ2, B30, B31, B32, B33, FJ3;
    float VA0, VA1, VA2, VA3, SB0, SB1, SB2, SB3;

    // Chunk boot: rows 0..3, A rows 0,1, P0 rows 0,1 (SB0, SB1).
    LOADROW(0, 0) LOADROW(1, 1) LOADROW(2, 2) LOADROW(3, 3)
    LOADA(0, 0) LOADA(1, 1)
    P0C(0, 0) P0C(1, 1)

    ST_FULL(0, 0, 2)  ST_FULL(1, 1, 3)  ST_FULL(2, 2, 0)  ST_FULL(3, 3, 1)
    ST_FULL(4, 0, 2)  ST_FULL(5, 1, 3)  ST_FULL(6, 2, 0)  ST_FULL(7, 3, 1)
    ST_FULL(8, 0, 2)  ST_FULL(9, 1, 3)  ST_FULL(10, 2, 0) ST_FULL(11, 3, 1)
    ST_FULL(12, 0, 2) ST_FULL(13, 1, 3) ST_FULL(14, 2, 0) ST_FULL(15, 3, 1)
    ST_FULL(16, 0, 2) ST_FULL(17, 1, 3) ST_FULL(18, 2, 0) ST_FULL(19, 3, 1)
    ST_FULL(20, 0, 2) ST_FULL(21, 1, 3) ST_FULL(22, 2, 0) ST_FULL(23, 3, 1)
    ST_FULL(24, 0, 2) ST_FULL(25, 1, 3) ST_FULL(26, 2, 0) ST_FULL(27, 3, 1)
    ST_NOLOAD(28, 0, 2) ST_NOLOAD(29, 1, 3)
    ST_TAIL(30, 2) ST_TAIL(31, 3)

    // Output: lane t (t<32): e_t = vp; pred_t = e_t/LR + f_t[j].
    {
      float v_out = fmaf(vp, 100.0f, v_fja);
      if (lane < 32) pb0[(size_t)(c * RCH + lane) * Dsc] = v_out;
    }

    // Deferred W update (once per chunk).
    w0 -= acc0; w1 -= acc1; w2 -= acc2; w3 -= acc3;

    // Handoff (proven): barrier -> stage c+2 over buf cb -> counted vmcnt(9)
    // (chunk c+1's 9 loads are older) -> barrier.
    __builtin_amdgcn_s_barrier();
    if (c + 2 < NCH) {
      STAGE(cb, c + 2);
      asm volatile("s_waitcnt vmcnt(9)" ::: "memory");
    } else {
      asm volatile("s_waitcnt vmcnt(0)" ::: "memory");
    }
    __builtin_amdgcn_s_barrier();
    __builtin_amdgcn_sched_barrier(0);
  }
#undef ST_FULL
#undef ST_NOLOAD
#undef ST_TAIL
#undef SOLVE
#undef P0C
#undef LOADA
#undef LOADROW
#undef STAGE
}

extern "C" void kernel_launch(void* const* d_in, const int* in_sizes, int n_in,
                              void* d_out, int out_size, void* d_ws, size_t ws_size,
                              hipStream_t stream) {
  const float* x  = (const float*)d_in[0];  // (B,S,D)
  const float* Wd = (const float*)d_in[1];  // (D,Ds)
  const float* bd = (const float*)d_in[2];  // (Ds)
  const float* Wu = (const float*)d_in[3];  // (Ds,D)
  const float* bu = (const float*)d_in[4];  // (D)
  float* out = (float*)d_out;               // (B,S,D)

  float* feat  = (float*)d_ws;                        // B*S*Ds f32 = 8 MB
  float* preds = feat + (size_t)Bc * Sc * Dsc;        // 8 MB
  float* Ahat  = preds + (size_t)Bc * Sc * Dsc;       // B*NCH*1024 f32 = 1 MB

  const int M = Bc * Sc;  // 8192
  dim3 blk(256);

  // feat = x @ W_down + b_down   (M=8192, N=256, K=1024)
  gemm_bias<<<dim3(M / 64, Dsc / 64), blk, 0, stream>>>(
      x, Wd, bd, nullptr, feat, M, Dsc, Dc);

  // per-chunk strict-lower Gram matrices (parallel, recurrence-independent)
  gram_chunks<<<dim3(Bc * NCH), blk, 0, stream>>>(feat, Ahat);

  // chunked sequential scan -> preds
  ttt_scan<<<dim3(Bc * Dsc / 4), blk, 0, stream>>>(feat, Ahat, preds);

  // out = preds @ W_up + b_up + x   (M=8192, N=1024, K=256)
  gemm_bias<<<dim3(M / 64, Dc / 64), blk, 0, stream>>>(
      preds, Wu, bu, x, out, M, Dc, Dsc);
}